// Round 11
// baseline (466.418 us; speedup 1.0000x reference)
//
#include <hip/hip_runtime.h>
#include <hip/hip_bf16.h>
#include <math.h>
#include <stdint.h>

#define N_NODES 50000
#define N_EDGES 800000
#define HID 128
#define NGRAPH 256
#define NLAYER 2
#define CAP 64  // CSR slots per node; Poisson(16) tail beyond 64 ~ 1e-18

typedef __bf16 bf16x8 __attribute__((ext_vector_type(8)));
typedef __bf16 bf16x2 __attribute__((ext_vector_type(2)));
typedef float f32x4 __attribute__((ext_vector_type(4)));
typedef float f32x2 __attribute__((ext_vector_type(2)));

__device__ __forceinline__ float gelu_f(float v) {
    return 0.5f * v * (1.0f + erff(v * 0.70710678118654752f));
}

// fp8 e4m3 (OCP on gfx950) helpers
__device__ __forceinline__ void cvt4_fp8(uint32_t w, float* o) {
    f32x2 lo = __builtin_amdgcn_cvt_pk_f32_fp8(w, false);
    f32x2 hi = __builtin_amdgcn_cvt_pk_f32_fp8(w, true);
    o[0] = lo[0]; o[1] = lo[1]; o[2] = hi[0]; o[3] = hi[1];
}
__device__ __forceinline__ uint32_t pk4_fp8(float a, float b, float c, float d) {
    int w = __builtin_amdgcn_cvt_pk_fp8_f32(a, b, 0, false);
    w = __builtin_amdgcn_cvt_pk_fp8_f32(c, d, w, true);
    return (uint32_t)w;
}

// ---------------- mega-prep: scatter | encoder | tkv | repack | setup ----------------
// grid: [0,3125) scatter, [3125,28125) encoder, [28125,29149) tkv,
//       [29149,29277) repack, [29277,29281) setup.
__global__ __launch_bounds__(256) void prep_kernel(
    const int* __restrict__ tgt, const int* __restrict__ src,
    const int* __restrict__ sd, const int* __restrict__ sp,
    int* __restrict__ cnt, uint32_t* __restrict__ ei,
    const int* __restrict__ attr, const float* __restrict__ aemb,
    __bf16* __restrict__ xb,
    const float* __restrict__ de, const float* __restrict__ pe,
    const float* __restrict__ Wk, const float* __restrict__ Wv,
    __bf16* __restrict__ tkv,
    const float* __restrict__ Wq, const float* __restrict__ Wa,
    const float* __restrict__ Wmid, const float* __restrict__ Wo,
    __bf16* __restrict__ wqkvf, __bf16* __restrict__ waf,
    __bf16* __restrict__ wmidf, __bf16* __restrict__ wof,
    const int* __restrict__ batch, const float* __restrict__ bout,
    const float* __restrict__ bq, const float* __restrict__ bk,
    const float* __restrict__ bv,
    float* __restrict__ invc, float* __restrict__ outp, float* __restrict__ bqkv) {
    __shared__ float sde[128];
    int b = blockIdx.x;
    int tid = threadIdx.x;
    if (b < 3125) {
        // ---- CSR scatter: CAP slots/node, packed 4B payload src | md<<16 ----
        int e = b * 256 + tid;  // 3125*256 == N_EDGES
        int t = tgt[e];
        int r = atomicAdd(&cnt[t], 1);
        if (r < CAP) ei[(t << 6) + r] = (uint32_t)src[e] | ((uint32_t)((sd[e] << 4) | sp[e]) << 16);
    } else if (b < 28125) {
        // ---- node encoder (bf16 only; fp32 x stream eliminated) ----
        int idx = (b - 3125) * 256 + tid;  // N*128
        int n = idx >> 7, c = idx & 127;
        const int4 a = *(const int4*)(attr + n * 4);
        float s = aemb[(0 * 64 + a.x) * 128 + c] + aemb[(1 * 64 + a.y) * 128 + c] +
                  aemb[(2 * 64 + a.z) * 128 + c] + aemb[(3 * 64 + a.w) * 128 + c];
        xb[idx] = (__bf16)s;
    } else if (b < 29149) {
        // ---- combined relational tables (both layers) from fp32 ----
        int bb = b - 28125;
        int l = bb >> 9;
        int md = bb & 511;
        int dd = md >> 4, pp = md & 15;
        int c = tid;
        if (c < 128) sde[c] = de[l * 4096 + dd * 128 + c] + pe[l * 2048 + pp * 128 + c];
        __syncthreads();
        const float* W = (c < 128) ? (Wk + l * 16384) : (Wv + l * 16384);
        int cc = c & 127;
        float acc = 0.f;
#pragma unroll 4
        for (int k = 0; k < 128; k++) acc = fmaf(sde[k], W[k * 128 + cc], acc);
        tkv[(size_t)bb * 256 + c] = (__bf16)acc;
    } else if (b < 29277) {
        // ---- weight repack: fp32 [CI][CO] -> bf16 fragment units, sigma perm ----
        int u = (b - 29149) * 256 + tid;
        int l = u >> 14, r = u & 16383;
        const float* srcp;
        __bf16* dstp;
        int kg, scol, srcCO;
        if (r < 6144) {  // fused QKV, CO=384
            kg = r / 384;
            int uu = r % 384;
            int sec = uu >> 7, cc = uu & 127;
            scol = ((cc & 15) << 3) | (cc >> 4);
            const float* Ws = (sec == 0) ? Wq : (sec == 1) ? Wk : Wv;
            srcp = Ws + l * 16384;
            srcCO = 128;
            dstp = wqkvf + (size_t)l * 49152 + (size_t)r * 8;
        } else if (r < 8192) {  // Wa
            int rr = r - 6144;
            kg = rr >> 7;
            int cc = rr & 127;
            scol = ((cc & 15) << 3) | (cc >> 4);
            srcp = Wa + l * 16384;
            srcCO = 128;
            dstp = waf + (size_t)l * 16384 + (size_t)rr * 8;
        } else if (r < 12288) {  // Wmid, CO=256
            int rr = r - 8192;
            kg = rr >> 8;
            int uu = rr & 255;
            int blk = uu >> 7, cc = uu & 127;
            scol = blk * 128 + (((cc & 15) << 3) | (cc >> 4));
            srcp = Wmid + l * 32768;
            srcCO = 256;
            dstp = wmidf + (size_t)l * 32768 + (size_t)rr * 8;
        } else {  // Wo, CI=256
            int rr = r - 12288;
            kg = rr >> 7;
            int cc = rr & 127;
            scol = ((cc & 15) << 3) | (cc >> 4);
            srcp = Wo + l * 32768;
            srcCO = 128;
            dstp = wof + (size_t)l * 32768 + (size_t)rr * 8;
        }
        bf16x8 o;
#pragma unroll
        for (int j = 0; j < 8; j++) o[j] = (__bf16)srcp[(kg * 8 + j) * srcCO + scol];
        *(bf16x8*)dstp = o;
    } else {
        // ---- setup: per-graph invc + out init, fused QKV bias ----
        int sb = b - 29277;
        if (sb == 0) {
            int g = tid;
            int lo = 0, hi = N_NODES;
            while (lo < hi) { int mid = (lo + hi) >> 1; if (batch[mid] < g) lo = mid + 1; else hi = mid; }
            int start = lo;
            lo = start; hi = N_NODES;
            while (lo < hi) { int mid = (lo + hi) >> 1; if (batch[mid] < g + 1) lo = mid + 1; else hi = mid; }
            int c2 = lo - start;
            invc[g] = 1.0f / fmaxf((float)c2, 1.0f);
            outp[g] = bout[0];
        } else {
            int r = (sb - 1) * 256 + tid;
            int l = r / 384, c = r % 384;
            float v = (c < 128) ? bq[l * 128 + c]
                    : (c < 256) ? bk[l * 128 + c - 128]
                                : bv[l * 128 + c - 256];
            bqkv[r] = v;
        }
    }
}

// ---------------- QKV GEMM: wave 32 rows x 128 cols, block 128 rows ----------------
// Q -> bf16 Qb; K,V -> fp8 kv8 (N x 256B). grid (3, ceil(M/128)).
__global__ __launch_bounds__(256) void qkv_gemm(
    const __bf16* __restrict__ A, const __bf16* __restrict__ Wf,
    const float* __restrict__ bias, __bf16* __restrict__ Qb,
    uint8_t* __restrict__ kv8, int M) {
    int lane = threadIdx.x & 63;
    int wv = threadIdx.x >> 6;
    int row0 = blockIdx.y * 128 + wv * 32;
    int sec = blockIdx.x;
    int col0 = sec * 128;
    if (row0 >= M) return;
    int quad = lane >> 4, tq = lane & 15;
    f32x4 acc[2][8] = {};
#pragma unroll
    for (int k0 = 0; k0 < 128; k0 += 32) {
        bf16x8 af[2];
#pragma unroll
        for (int mt = 0; mt < 2; mt++) {
            int rr = row0 + mt * 16 + tq;
            if (rr >= M) rr = M - 1;
            af[mt] = *(const bf16x8*)(A + (size_t)rr * 128 + k0 + quad * 8);
        }
#pragma unroll
        for (int nt = 0; nt < 8; nt++) {
            bf16x8 bfr = *(const bf16x8*)(Wf + ((size_t)((k0 >> 3) + quad) * 384 + col0 + nt * 16 + tq) * 8);
            acc[0][nt] = __builtin_amdgcn_mfma_f32_16x16x32_bf16(af[0], bfr, acc[0][nt], 0, 0, 0);
            acc[1][nt] = __builtin_amdgcn_mfma_f32_16x16x32_bf16(af[1], bfr, acc[1][nt], 0, 0, 0);
        }
    }
    int cb = tq * 8;
    float bia[8];
#pragma unroll
    for (int t = 0; t < 8; t++) bia[t] = bias[col0 + cb + t];
#pragma unroll
    for (int mt = 0; mt < 2; mt++) {
#pragma unroll
        for (int v = 0; v < 4; v++) {
            int rr = row0 + mt * 16 + quad * 4 + v;
            if (rr >= M) continue;
            float val[8];
#pragma unroll
            for (int t = 0; t < 8; t++) val[t] = acc[mt][t][v] + bia[t];
            if (sec == 0) {
                bf16x8 ov;
#pragma unroll
                for (int t = 0; t < 8; t++) ov[t] = (__bf16)val[t];
                *(bf16x8*)(Qb + (size_t)rr * 128 + cb) = ov;
            } else {
                uint2 st;
                st.x = pk4_fp8(val[0], val[1], val[2], val[3]);
                st.y = pk4_fp8(val[4], val[5], val[6], val[7]);
                *(uint2*)(kv8 + (size_t)rr * 256 + (sec - 1) * 128 + cb) = st;
            }
        }
    }
}

// ---------------- MFMA GEMM (FFN): wave 32 rows x 128 cols, block 128 rows ----------
// All activations bf16 (fp32 residual stream eliminated; GEMM inputs were
// already bf16-rounded, output is graph-pooled so rounding washes out).
template <int CI, bool GOUT, bool LN, bool POOL>
__global__ __launch_bounds__(256) void mfma_gemm(
    const __bf16* __restrict__ A, const __bf16* __restrict__ Wf,
    const float* __restrict__ bias, const __bf16* __restrict__ res,
    const float* __restrict__ lng, const float* __restrict__ lnb,
    __bf16* outb,
    const int* __restrict__ batch, const float* __restrict__ invc,
    const float* __restrict__ WoutV, float* __restrict__ outp,
    int M, int CO) {
    __shared__ float ps[POOL ? NGRAPH : 1];
    int lane = threadIdx.x & 63;
    int wv = threadIdx.x >> 6;
    int row0 = blockIdx.y * 128 + wv * 32;
    int col0 = blockIdx.x * 128;
    bool active = row0 < M;
    if (POOL) {
        ps[threadIdx.x] = 0.f;
        __syncthreads();
    } else if (!active) {
        return;
    }
    int quad = lane >> 4, tq = lane & 15;
    if (active) {
        f32x4 acc[2][8] = {};
#pragma unroll
        for (int k0 = 0; k0 < CI; k0 += 32) {
            bf16x8 af[2];
#pragma unroll
            for (int mt = 0; mt < 2; mt++) {
                int rr = row0 + mt * 16 + tq;
                if (rr >= M) rr = M - 1;
                af[mt] = *(const bf16x8*)(A + (size_t)rr * CI + k0 + quad * 8);
            }
#pragma unroll
            for (int nt = 0; nt < 8; nt++) {
                bf16x8 bfr = *(const bf16x8*)(Wf + ((size_t)((k0 >> 3) + quad) * CO + col0 + nt * 16 + tq) * 8);
                acc[0][nt] = __builtin_amdgcn_mfma_f32_16x16x32_bf16(af[0], bfr, acc[0][nt], 0, 0, 0);
                acc[1][nt] = __builtin_amdgcn_mfma_f32_16x16x32_bf16(af[1], bfr, acc[1][nt], 0, 0, 0);
            }
        }
        int cb = col0 + tq * 8;
        float bia[8] = {};
        if (bias) {
#pragma unroll
            for (int t = 0; t < 8; t++) bia[t] = bias[cb + t];
        }
        float gv[8], bv2[8];
        if (LN) {
#pragma unroll
            for (int t = 0; t < 8; t++) { gv[t] = lng[cb + t]; bv2[t] = lnb[cb + t]; }
        }
        float wo8[8];
        if (POOL) {
#pragma unroll
            for (int t = 0; t < 8; t++) wo8[t] = WoutV[cb + t];
        }
#pragma unroll
        for (int mt = 0; mt < 2; mt++) {
#pragma unroll
            for (int v = 0; v < 4; v++) {
                int rr = row0 + mt * 16 + quad * 4 + v;
                if (rr >= M) continue;
                float val[8];
#pragma unroll
                for (int nt = 0; nt < 8; nt++) val[nt] = acc[mt][nt][v] + bia[nt];
                if (res) {  // bf16 residual (CO==128 only)
                    bf16x8 rv = *(const bf16x8*)(res + (size_t)rr * 128 + tq * 8);
#pragma unroll
                    for (int t = 0; t < 8; t++) val[t] += (float)rv[t];
                }
                if (GOUT) {
#pragma unroll
                    for (int t = 0; t < 8; t++) val[t] = gelu_f(val[t]);
                }
                if (LN) {
                    float s = 0.f, s2 = 0.f;
#pragma unroll
                    for (int t = 0; t < 8; t++) { s += val[t]; s2 = fmaf(val[t], val[t], s2); }
#pragma unroll
                    for (int o = 1; o < 16; o <<= 1) {
                        s += __shfl_xor(s, o);
                        s2 += __shfl_xor(s2, o);
                    }
                    float m = s * (1.0f / 128.0f);
                    float var = s2 * (1.0f / 128.0f) - m * m;
                    float rs = rsqrtf(var + 1e-5f);
#pragma unroll
                    for (int t = 0; t < 8; t++) val[t] = (val[t] - m) * rs * gv[t] + bv2[t];
                }
                if (outb) {
                    bf16x8 ov;
#pragma unroll
                    for (int t = 0; t < 8; t++) ov[t] = (__bf16)val[t];
                    *(bf16x8*)(outb + (size_t)rr * CO + cb) = ov;
                }
                if (POOL) {
                    float dot = 0.f;
#pragma unroll
                    for (int t = 0; t < 8; t++) dot = fmaf(val[t], wo8[t], dot);
#pragma unroll
                    for (int o = 1; o < 16; o <<= 1) dot += __shfl_xor(dot, o);
                    if (tq == 0) {
                        int g = batch[rr];
                        atomicAdd(&ps[g], dot * invc[g]);  // LDS atomic: fast, per-CU
                    }
                }
            }
        }
    }
    if (POOL) {
        __syncthreads();
        float pv = ps[threadIdx.x];
        if (pv != 0.f) atomicAdd(&outp[threadIdx.x], pv);
    }
}

// ---------------- attention: one wave per node, 8 edges in flight, 1 head/lane ----
// CAP-CSR; fp8 K/V; 2-deep pipeline; conflict-aware LDS merge (r10 layout).
__global__ __launch_bounds__(256) void attn_kernel(
    const __bf16* __restrict__ Qb, const uint8_t* __restrict__ kv8,
    const __bf16* __restrict__ tkv,
    const int* __restrict__ cnt, const uint32_t* __restrict__ ei,
    __bf16* __restrict__ outb) {
    __shared__ float red[4][1376];  // 8 slots x 172 words per wave
    int wv = threadIdx.x >> 6;
    int i = blockIdx.x * 4 + wv;  // N = 50000 = 12500*4: no tail
    int lane = threadIdx.x & 63;
    int slot = lane >> 3, h = lane & 7;
    int ch0 = h * 16;
    const __bf16* qp = Qb + (size_t)i * 128 + ch0;
    bf16x8 q0 = *(const bf16x8*)qp;
    bf16x8 q1 = *(const bf16x8*)(qp + 8);
    float qf[16];
#pragma unroll
    for (int t = 0; t < 8; t++) { qf[t] = (float)q0[t]; qf[8 + t] = (float)q1[t]; }
    int deg = cnt[i];
    if (deg > CAP) deg = CAP;
    int p0 = i << 6;
    int p1 = p0 + deg;
    float l = 0.f;
    float a[16] = {};
    int p = p0 + slot;
    uint32_t w1 = 0, w2 = 0;
    if (p < p1) w1 = ei[p];
    if (p + 8 < p1) w2 = ei[p + 8];
    uint4 kw, vw;
    bf16x8 t0, t1, u0, u1;
    {
        int j = w1 & 0xffff, md = w1 >> 16;
        const uint8_t* kr = kv8 + (size_t)j * 256 + ch0;
        kw = *(const uint4*)kr;
        vw = *(const uint4*)(kr + 128);
        const __bf16* tr = tkv + md * 256 + ch0;
        t0 = *(const bf16x8*)tr;
        t1 = *(const bf16x8*)(tr + 8);
        u0 = *(const bf16x8*)(tr + 128);
        u1 = *(const bf16x8*)(tr + 136);
    }
    while (p < p1) {
        uint4 kwn, vwn;
        bf16x8 t0n, t1n, u0n, u1n;
        {
            int j = w2 & 0xffff, md = w2 >> 16;
            const uint8_t* kr = kv8 + (size_t)j * 256 + ch0;
            kwn = *(const uint4*)kr;
            vwn = *(const uint4*)(kr + 128);
            const __bf16* tr = tkv + md * 256 + ch0;
            t0n = *(const bf16x8*)tr;
            t1n = *(const bf16x8*)(tr + 8);
            u0n = *(const bf16x8*)(tr + 128);
            u1n = *(const bf16x8*)(tr + 136);
        }
        uint32_t w3 = w2;
        if (p + 16 < p1) w3 = ei[p + 16];
        float kf[16], vf[16];
        cvt4_fp8(kw.x, kf + 0); cvt4_fp8(kw.y, kf + 4);
        cvt4_fp8(kw.z, kf + 8); cvt4_fp8(kw.w, kf + 12);
        cvt4_fp8(vw.x, vf + 0); cvt4_fp8(vw.y, vf + 4);
        cvt4_fp8(vw.z, vf + 8); cvt4_fp8(vw.w, vf + 12);
        float s = 0.f;
#pragma unroll
        for (int t = 0; t < 8; t++) {
            s = fmaf(qf[t], kf[t] + (float)t0[t], s);
            s = fmaf(qf[8 + t], kf[8 + t] + (float)t1[t], s);
        }
        float pe = __expf(s * 0.25f);  // 1/sqrt(DK)
        l += pe;
#pragma unroll
        for (int t = 0; t < 8; t++) {
            a[t] = fmaf(pe, vf[t] + (float)u0[t], a[t]);
            a[8 + t] = fmaf(pe, vf[8 + t] + (float)u1[t], a[8 + t]);
        }
        kw = kwn; vw = vwn; t0 = t0n; t1 = t1n; u0 = u0n; u1 = u1n;
        w2 = w3;
        p += 8;
    }
    // ---- LDS slot-merge epilogue (same-wave produce/consume: no barrier) ----
    float* rw = red[wv] + slot * 172 + 20 * h;  // pad(16h) = 20h
    *(float4*)(rw + 0) = make_float4(a[0], a[1], a[2], a[3]);
    *(float4*)(rw + 4) = make_float4(a[4], a[5], a[6], a[7]);
    *(float4*)(rw + 8) = make_float4(a[8], a[9], a[10], a[11]);
    *(float4*)(rw + 12) = make_float4(a[12], a[13], a[14], a[15]);
    red[wv][slot * 172 + 156 + h] = l;
    asm volatile("" ::: "memory");  // keep ds_reads after ds_writes (DS in-order per wave)
    int pc = 2 * lane + 4 * (lane >> 3);  // pad(2*lane)
    int hh = lane >> 3;
    float s0 = 0.f, s1 = 0.f, ls = 0.f;
#pragma unroll
    for (int s = 0; s < 8; s++) {
        float2 v = *(const float2*)(red[wv] + s * 172 + pc);
        s0 += v.x;
        s1 += v.y;
        ls += red[wv][s * 172 + 156 + hh];
    }
    float inv = 1.0f / (ls + 1e-16f);
    bf16x2 o2;
    o2[0] = (__bf16)gelu_f(s0 * inv);
    o2[1] = (__bf16)gelu_f(s1 * inv);
    *(bf16x2*)(outb + (size_t)i * 128 + 2 * lane) = o2;
}

extern "C" void kernel_launch(void* const* d_in, const int* in_sizes, int n_in,
                              void* d_out, int out_size, void* d_ws, size_t ws_size,
                              hipStream_t stream) {
    const int N = N_NODES, E = N_EDGES;
    const int* node_attr = (const int*)d_in[0];
    const int* batch_idx = (const int*)d_in[1];
    const int* edge_index = (const int*)d_in[2];
    const int* strat_dist = (const int*)d_in[3];
    const int* strat_path = (const int*)d_in[4];
    const float* atom_emb = (const float*)d_in[5];
    const float* dist_emb = (const float*)d_in[6];
    const float* path_emb = (const float*)d_in[7];
    const float* Wq = (const float*)d_in[8];
    const float* bq = (const float*)d_in[9];
    const float* Wk = (const float*)d_in[10];
    const float* bk = (const float*)d_in[11];
    const float* Wv = (const float*)d_in[12];
    const float* bv = (const float*)d_in[13];
    const float* Wa = (const float*)d_in[14];
    const float* ba = (const float*)d_in[15];
    const float* ln1g = (const float*)d_in[16];
    const float* ln1b = (const float*)d_in[17];
    const float* Wmid = (const float*)d_in[18];
    const float* bmid = (const float*)d_in[19];
    const float* Wo = (const float*)d_in[20];
    const float* bo = (const float*)d_in[21];
    const float* ln2g = (const float*)d_in[22];
    const float* ln2b = (const float*)d_in[23];
    const float* Wout = (const float*)d_in[24];
    const float* bout = (const float*)d_in[25];
    float* out = (float*)d_out;

    const int* src = edge_index;
    const int* tgt = edge_index + E;

    // ---- workspace layout (fp32 x stream removed) ----
    size_t NF = (size_t)N * HID;          // 6.4e6
    float* invc = (float*)d_ws;           // 256
    float* bqkv = invc + 256;             // 768
    __bf16* xb = (__bf16*)(bqkv + 768);   // NF
    __bf16* Qb = xb + NF;                 // NF
    __bf16* ab = Qb + NF;                 // NF: gelu(aggr), then h bf16 (in-place)
    __bf16* midb = ab + NF;               // 2*NF (N x 256)
    __bf16* tkv = midb + 2 * NF;          // 2 * 512*256
    __bf16* wqkvf = tkv + 262144;         // 2*49152
    __bf16* waf = wqkvf + 98304;          // 2*16384
    __bf16* wmidf = waf + 32768;          // 2*32768
    __bf16* wof = wmidf + 65536;          // 2*32768
    uint8_t* kv8 = (uint8_t*)(wof + 65536);     // N*256 bytes fp8 (K|V)
    uint32_t* ei = (uint32_t*)(kv8 + (size_t)N * 256);  // N*CAP packed
    int* cnt = (int*)(ei + (size_t)N * CAP);    // N

    // ---- prep: memset cnt + one merged dispatch for all setup work ----
    hipMemsetAsync(cnt, 0, N * sizeof(int), stream);
    prep_kernel<<<29281, 256, 0, stream>>>(
        tgt, src, strat_dist, strat_path, cnt, ei,
        node_attr, atom_emb, xb,
        dist_emb, path_emb, Wk, Wv, tkv,
        Wq, Wa, Wmid, Wo, wqkvf, waf, wmidf, wof,
        batch_idx, bout, bq, bk, bv, invc, out, bqkv);

    const int GB = (N + 127) / 128;  // 391 row-blocks (128 rows/block)
    const int AB = (N + 3) / 4;      // 12500 attn blocks (1 node/wave)

    for (int l = 0; l < NLAYER; ++l) {
        // fused QKV: Q -> bf16, K/V -> fp8 packed per node
        qkv_gemm<<<dim3(3, GB), 256, 0, stream>>>(
            xb, wqkvf + l * 49152, bqkv + l * 384, Qb, kv8, N);

        // segment-softmax attention; writes gelu(aggr) bf16 into ab
        attn_kernel<<<AB, 256, 0, stream>>>(Qb, kv8, tkv + l * 131072, cnt, ei, ab);

        // h = LN1(gelu(aggr)@Wa + ba + xb) -> ab bf16 (in-place, wave-local rows)
        mfma_gemm<128, false, true, false><<<dim3(1, GB), 256, 0, stream>>>(
            ab, waf + l * 16384, ba + l * 128, xb, ln1g + l * 128, ln1b + l * 128,
            ab, nullptr, nullptr, nullptr, nullptr, N, 128);
        // mid = gelu(h@Wmid + bmid) -> bf16 N x 256
        mfma_gemm<128, true, false, false><<<dim3(2, GB), 256, 0, stream>>>(
            ab, wmidf + l * 32768, bmid + l * 256, nullptr, nullptr, nullptr,
            midb, nullptr, nullptr, nullptr, nullptr, N, 256);
        // x = LN2(mid@Wo + bo + h); last layer: fused pooled readout
        if (l < NLAYER - 1) {
            mfma_gemm<256, false, true, false><<<dim3(1, GB), 256, 0, stream>>>(
                midb, wof + l * 32768, bo + l * 128, ab, ln2g + l * 128, ln2b + l * 128,
                xb, nullptr, nullptr, nullptr, nullptr, N, 128);
        } else {
            mfma_gemm<256, false, true, true><<<dim3(1, GB), 256, 0, stream>>>(
                midb, wof + l * 32768, bo + l * 128, ab, ln2g + l * 128, ln2b + l * 128,
                nullptr, batch_idx, invc, Wout, out, N, 128);
        }
    }
}

// Round 12
// 429.391 us; speedup vs baseline: 1.0862x; 1.0862x over previous
//
#include <hip/hip_runtime.h>
#include <hip/hip_bf16.h>
#include <math.h>
#include <stdint.h>

#define N_NODES 50000
#define N_EDGES 800000
#define HID 128
#define NGRAPH 256
#define NLAYER 2
#define CAP 64  // CSR slots per node; Poisson(16) tail beyond 64 ~ 1e-18

typedef __bf16 bf16x8 __attribute__((ext_vector_type(8)));
typedef __bf16 bf16x2 __attribute__((ext_vector_type(2)));
typedef float f32x4 __attribute__((ext_vector_type(4)));
typedef float f32x2 __attribute__((ext_vector_type(2)));

__device__ __forceinline__ float gelu_f(float v) {
    return 0.5f * v * (1.0f + erff(v * 0.70710678118654752f));
}

// fp8 e4m3 (OCP on gfx950) helpers
__device__ __forceinline__ void cvt4_fp8(uint32_t w, float* o) {
    f32x2 lo = __builtin_amdgcn_cvt_pk_f32_fp8(w, false);
    f32x2 hi = __builtin_amdgcn_cvt_pk_f32_fp8(w, true);
    o[0] = lo[0]; o[1] = lo[1]; o[2] = hi[0]; o[3] = hi[1];
}
__device__ __forceinline__ uint32_t pk4_fp8(float a, float b, float c, float d) {
    int w = __builtin_amdgcn_cvt_pk_fp8_f32(a, b, 0, false);
    w = __builtin_amdgcn_cvt_pk_fp8_f32(c, d, w, true);
    return (uint32_t)w;
}

// ---------------- prep: encoder | tkv | repack | setup (scatter moved out) --------
// grid: [0,25000) encoder, [25000,26024) tkv, [26024,26152) repack, [26152,26156) setup
__global__ __launch_bounds__(256) void prep_kernel(
    const int* __restrict__ attr, const float* __restrict__ aemb,
    __bf16* __restrict__ xb,
    const float* __restrict__ de, const float* __restrict__ pe,
    const float* __restrict__ Wk, const float* __restrict__ Wv,
    __bf16* __restrict__ tkv,
    const float* __restrict__ Wq, const float* __restrict__ Wa,
    const float* __restrict__ Wmid, const float* __restrict__ Wo,
    __bf16* __restrict__ wqkvf, __bf16* __restrict__ waf,
    __bf16* __restrict__ wmidf, __bf16* __restrict__ wof,
    const int* __restrict__ batch, const float* __restrict__ bout,
    const float* __restrict__ bq, const float* __restrict__ bk,
    const float* __restrict__ bv,
    float* __restrict__ invc, float* __restrict__ outp, float* __restrict__ bqkv) {
    __shared__ float sde[128];
    int b = blockIdx.x;
    int tid = threadIdx.x;
    if (b < 25000) {
        // ---- node encoder (bf16 only) ----
        int idx = b * 256 + tid;  // N*128
        int n = idx >> 7, c = idx & 127;
        const int4 a = *(const int4*)(attr + n * 4);
        float s = aemb[(0 * 64 + a.x) * 128 + c] + aemb[(1 * 64 + a.y) * 128 + c] +
                  aemb[(2 * 64 + a.z) * 128 + c] + aemb[(3 * 64 + a.w) * 128 + c];
        xb[idx] = (__bf16)s;
    } else if (b < 26024) {
        // ---- combined relational tables (both layers) from fp32 ----
        int bb = b - 25000;
        int l = bb >> 9;
        int md = bb & 511;
        int dd = md >> 4, pp = md & 15;
        int c = tid;
        if (c < 128) sde[c] = de[l * 4096 + dd * 128 + c] + pe[l * 2048 + pp * 128 + c];
        __syncthreads();
        const float* W = (c < 128) ? (Wk + l * 16384) : (Wv + l * 16384);
        int cc = c & 127;
        float acc = 0.f;
#pragma unroll 4
        for (int k = 0; k < 128; k++) acc = fmaf(sde[k], W[k * 128 + cc], acc);
        tkv[(size_t)bb * 256 + c] = (__bf16)acc;
    } else if (b < 26152) {
        // ---- weight repack: fp32 [CI][CO] -> bf16 fragment units, sigma perm ----
        int u = (b - 26024) * 256 + tid;
        int l = u >> 14, r = u & 16383;
        const float* srcp;
        __bf16* dstp;
        int kg, scol, srcCO;
        if (r < 6144) {  // fused QKV, CO=384
            kg = r / 384;
            int uu = r % 384;
            int sec = uu >> 7, cc = uu & 127;
            scol = ((cc & 15) << 3) | (cc >> 4);
            const float* Ws = (sec == 0) ? Wq : (sec == 1) ? Wk : Wv;
            srcp = Ws + l * 16384;
            srcCO = 128;
            dstp = wqkvf + (size_t)l * 49152 + (size_t)r * 8;
        } else if (r < 8192) {  // Wa
            int rr = r - 6144;
            kg = rr >> 7;
            int cc = rr & 127;
            scol = ((cc & 15) << 3) | (cc >> 4);
            srcp = Wa + l * 16384;
            srcCO = 128;
            dstp = waf + (size_t)l * 16384 + (size_t)rr * 8;
        } else if (r < 12288) {  // Wmid, CO=256
            int rr = r - 8192;
            kg = rr >> 8;
            int uu = rr & 255;
            int blk = uu >> 7, cc = uu & 127;
            scol = blk * 128 + (((cc & 15) << 3) | (cc >> 4));
            srcp = Wmid + l * 32768;
            srcCO = 256;
            dstp = wmidf + (size_t)l * 32768 + (size_t)rr * 8;
        } else {  // Wo, CI=256
            int rr = r - 12288;
            kg = rr >> 7;
            int cc = rr & 127;
            scol = ((cc & 15) << 3) | (cc >> 4);
            srcp = Wo + l * 32768;
            srcCO = 128;
            dstp = wof + (size_t)l * 32768 + (size_t)rr * 8;
        }
        bf16x8 o;
#pragma unroll
        for (int j = 0; j < 8; j++) o[j] = (__bf16)srcp[(kg * 8 + j) * srcCO + scol];
        *(bf16x8*)dstp = o;
    } else {
        // ---- setup: per-graph invc + out init, fused QKV bias ----
        int sb = b - 26152;
        if (sb == 0) {
            int g = tid;
            int lo = 0, hi = N_NODES;
            while (lo < hi) { int mid = (lo + hi) >> 1; if (batch[mid] < g) lo = mid + 1; else hi = mid; }
            int start = lo;
            lo = start; hi = N_NODES;
            while (lo < hi) { int mid = (lo + hi) >> 1; if (batch[mid] < g + 1) lo = mid + 1; else hi = mid; }
            int c2 = lo - start;
            invc[g] = 1.0f / fmaxf((float)c2, 1.0f);
            outp[g] = bout[0];
        } else {
            int r = (sb - 1) * 256 + tid;
            int l = r / 384, c = r % 384;
            float v = (c < 128) ? bq[l * 128 + c]
                    : (c < 256) ? bk[l * 128 + c - 128]
                                : bv[l * 128 + c - 256];
            bqkv[r] = v;
        }
    }
}

// ---------------- QKV GEMM (+ CSR scatter fused into layer-0 dispatch) ------------
// blocks [0,scatN): scatter (2 edges/thread, independent atomic chains);
// blocks [scatN,..): QKV, wave 16 rows x 128 cols, block 64 rows.
// Scatter first so its long-latency atomic chain starts immediately; QKV backfills.
// attn (next dispatch) sees completed ei/cnt at the dispatch boundary.
#define SCATB 1563  // ceil(800000/512)
__global__ __launch_bounds__(256) void qkv_gemm(
    const __bf16* __restrict__ A, const __bf16* __restrict__ Wf,
    const float* __restrict__ bias, __bf16* __restrict__ Qb,
    uint8_t* __restrict__ kv8, int M, int scatN,
    const int* __restrict__ tgt, const int* __restrict__ src,
    const int* __restrict__ sd, const int* __restrict__ sp,
    int* __restrict__ cnt, uint32_t* __restrict__ ei) {
    int tid = threadIdx.x;
    if (blockIdx.x < (unsigned)scatN) {
        int e0 = blockIdx.x * 512 + tid;
        int e1 = e0 + 256;
        bool v1 = e1 < N_EDGES;  // e0 always < N_EDGES when scatN=SCATB... guard both
        bool v0 = e0 < N_EDGES;
        int t0 = 0, t1 = 0;
        uint32_t p0 = 0, p1 = 0;
        if (v0) {
            t0 = tgt[e0];
            p0 = (uint32_t)src[e0] | ((uint32_t)((sd[e0] << 4) | sp[e0]) << 16);
        }
        if (v1) {
            t1 = tgt[e1];
            p1 = (uint32_t)src[e1] | ((uint32_t)((sd[e1] << 4) | sp[e1]) << 16);
        }
        int r0 = CAP, r1 = CAP;
        if (v0) r0 = atomicAdd(&cnt[t0], 1);
        if (v1) r1 = atomicAdd(&cnt[t1], 1);
        if (v0 && r0 < CAP) ei[(t0 << 6) + r0] = p0;
        if (v1 && r1 < CAP) ei[(t1 << 6) + r1] = p1;
        return;
    }
    int bq = blockIdx.x - scatN;
    int sec = bq % 3;           // consecutive blocks share A rows -> L2 reuse
    int rowblk = bq / 3;
    int lane = tid & 63;
    int wv = tid >> 6;
    int row0 = rowblk * 64 + wv * 16;
    int col0 = sec * 128;
    if (row0 >= M) return;
    int quad = lane >> 4, tq = lane & 15;
    f32x4 acc[8] = {};
#pragma unroll
    for (int k0 = 0; k0 < 128; k0 += 32) {
        int rr = row0 + tq;
        if (rr >= M) rr = M - 1;
        bf16x8 af = *(const bf16x8*)(A + (size_t)rr * 128 + k0 + quad * 8);
#pragma unroll
        for (int nt = 0; nt < 8; nt++) {
            bf16x8 bfr = *(const bf16x8*)(Wf + ((size_t)((k0 >> 3) + quad) * 384 + col0 + nt * 16 + tq) * 8);
            acc[nt] = __builtin_amdgcn_mfma_f32_16x16x32_bf16(af, bfr, acc[nt], 0, 0, 0);
        }
    }
    int cb = tq * 8;
    float bia[8];
#pragma unroll
    for (int t = 0; t < 8; t++) bia[t] = bias[col0 + cb + t];
#pragma unroll
    for (int v = 0; v < 4; v++) {
        int rr = row0 + quad * 4 + v;
        if (rr >= M) continue;
        float val[8];
#pragma unroll
        for (int t = 0; t < 8; t++) val[t] = acc[t][v] + bia[t];
        if (sec == 0) {
            bf16x8 ov;
#pragma unroll
            for (int t = 0; t < 8; t++) ov[t] = (__bf16)val[t];
            *(bf16x8*)(Qb + (size_t)rr * 128 + cb) = ov;
        } else {
            uint2 st;
            st.x = pk4_fp8(val[0], val[1], val[2], val[3]);
            st.y = pk4_fp8(val[4], val[5], val[6], val[7]);
            *(uint2*)(kv8 + (size_t)rr * 256 + (sec - 1) * 128 + cb) = st;
        }
    }
}

// ---------------- MFMA GEMM (FFN): r10 shape — wave 16 rows x 128 cols, block 64 --
// All activations bf16. grid (CO/128, ceil(M/64)).
template <int CI, bool GOUT, bool LN, bool POOL>
__global__ __launch_bounds__(256) void mfma_gemm(
    const __bf16* __restrict__ A, const __bf16* __restrict__ Wf,
    const float* __restrict__ bias, const __bf16* __restrict__ res,
    const float* __restrict__ lng, const float* __restrict__ lnb,
    __bf16* outb,
    const int* __restrict__ batch, const float* __restrict__ invc,
    const float* __restrict__ WoutV, float* __restrict__ outp,
    int M, int CO) {
    __shared__ float ps[POOL ? NGRAPH : 1];
    int lane = threadIdx.x & 63;
    int wv = threadIdx.x >> 6;
    int row0 = blockIdx.y * 64 + wv * 16;
    int col0 = blockIdx.x * 128;
    bool active = row0 < M;
    if (POOL) {
        ps[threadIdx.x] = 0.f;
        __syncthreads();
    } else if (!active) {
        return;
    }
    int quad = lane >> 4, tq = lane & 15;
    if (active) {
        f32x4 acc[8] = {};
#pragma unroll
        for (int k0 = 0; k0 < CI; k0 += 32) {
            int rr = row0 + tq;
            if (rr >= M) rr = M - 1;
            bf16x8 af = *(const bf16x8*)(A + (size_t)rr * CI + k0 + quad * 8);
#pragma unroll
            for (int nt = 0; nt < 8; nt++) {
                bf16x8 bfr = *(const bf16x8*)(Wf + ((size_t)((k0 >> 3) + quad) * CO + col0 + nt * 16 + tq) * 8);
                acc[nt] = __builtin_amdgcn_mfma_f32_16x16x32_bf16(af, bfr, acc[nt], 0, 0, 0);
            }
        }
        int cb = col0 + tq * 8;
        float bia[8] = {};
        if (bias) {
#pragma unroll
            for (int t = 0; t < 8; t++) bia[t] = bias[cb + t];
        }
        float gv[8], bv2[8];
        if (LN) {
#pragma unroll
            for (int t = 0; t < 8; t++) { gv[t] = lng[cb + t]; bv2[t] = lnb[cb + t]; }
        }
        float wo8[8];
        if (POOL) {
#pragma unroll
            for (int t = 0; t < 8; t++) wo8[t] = WoutV[cb + t];
        }
#pragma unroll
        for (int v = 0; v < 4; v++) {
            int rr = row0 + quad * 4 + v;
            if (rr >= M) continue;
            float val[8];
#pragma unroll
            for (int nt = 0; nt < 8; nt++) val[nt] = acc[nt][v] + bia[nt];
            if (res) {  // bf16 residual (CO==128 only)
                bf16x8 rv = *(const bf16x8*)(res + (size_t)rr * 128 + tq * 8);
#pragma unroll
                for (int t = 0; t < 8; t++) val[t] += (float)rv[t];
            }
            if (GOUT) {
#pragma unroll
                for (int t = 0; t < 8; t++) val[t] = gelu_f(val[t]);
            }
            if (LN) {
                float s = 0.f, s2 = 0.f;
#pragma unroll
                for (int t = 0; t < 8; t++) { s += val[t]; s2 = fmaf(val[t], val[t], s2); }
#pragma unroll
                for (int o = 1; o < 16; o <<= 1) {
                    s += __shfl_xor(s, o);
                    s2 += __shfl_xor(s2, o);
                }
                float m = s * (1.0f / 128.0f);
                float var = s2 * (1.0f / 128.0f) - m * m;
                float rs = rsqrtf(var + 1e-5f);
#pragma unroll
                for (int t = 0; t < 8; t++) val[t] = (val[t] - m) * rs * gv[t] + bv2[t];
            }
            if (outb) {
                bf16x8 ov;
#pragma unroll
                for (int t = 0; t < 8; t++) ov[t] = (__bf16)val[t];
                *(bf16x8*)(outb + (size_t)rr * CO + cb) = ov;
            }
            if (POOL) {
                float dot = 0.f;
#pragma unroll
                for (int t = 0; t < 8; t++) dot = fmaf(val[t], wo8[t], dot);
#pragma unroll
                for (int o = 1; o < 16; o <<= 1) dot += __shfl_xor(dot, o);
                if (tq == 0) {
                    int g = batch[rr];
                    atomicAdd(&ps[g], dot * invc[g]);  // LDS atomic: fast, per-CU
                }
            }
        }
    }
    if (POOL) {
        __syncthreads();
        float pv = ps[threadIdx.x];
        if (pv != 0.f) atomicAdd(&outp[threadIdx.x], pv);
    }
}

// ---------------- attention: one wave per node, 8 edges in flight, 1 head/lane ----
// CAP-CSR; fp8 K/V; 2-deep pipeline; conflict-aware LDS merge (r10 layout).
__global__ __launch_bounds__(256) void attn_kernel(
    const __bf16* __restrict__ Qb, const uint8_t* __restrict__ kv8,
    const __bf16* __restrict__ tkv,
    const int* __restrict__ cnt, const uint32_t* __restrict__ ei,
    __bf16* __restrict__ outb) {
    __shared__ float red[4][1376];  // 8 slots x 172 words per wave
    int wv = threadIdx.x >> 6;
    int i = blockIdx.x * 4 + wv;  // N = 50000 = 12500*4: no tail
    int lane = threadIdx.x & 63;
    int slot = lane >> 3, h = lane & 7;
    int ch0 = h * 16;
    const __bf16* qp = Qb + (size_t)i * 128 + ch0;
    bf16x8 q0 = *(const bf16x8*)qp;
    bf16x8 q1 = *(const bf16x8*)(qp + 8);
    float qf[16];
#pragma unroll
    for (int t = 0; t < 8; t++) { qf[t] = (float)q0[t]; qf[8 + t] = (float)q1[t]; }
    int deg = cnt[i];
    if (deg > CAP) deg = CAP;
    int p0 = i << 6;
    int p1 = p0 + deg;
    float l = 0.f;
    float a[16] = {};
    int p = p0 + slot;
    uint32_t w1 = 0, w2 = 0;
    if (p < p1) w1 = ei[p];
    if (p + 8 < p1) w2 = ei[p + 8];
    uint4 kw, vw;
    bf16x8 t0, t1, u0, u1;
    {
        int j = w1 & 0xffff, md = w1 >> 16;
        const uint8_t* kr = kv8 + (size_t)j * 256 + ch0;
        kw = *(const uint4*)kr;
        vw = *(const uint4*)(kr + 128);
        const __bf16* tr = tkv + md * 256 + ch0;
        t0 = *(const bf16x8*)tr;
        t1 = *(const bf16x8*)(tr + 8);
        u0 = *(const bf16x8*)(tr + 128);
        u1 = *(const bf16x8*)(tr + 136);
    }
    while (p < p1) {
        uint4 kwn, vwn;
        bf16x8 t0n, t1n, u0n, u1n;
        {
            int j = w2 & 0xffff, md = w2 >> 16;
            const uint8_t* kr = kv8 + (size_t)j * 256 + ch0;
            kwn = *(const uint4*)kr;
            vwn = *(const uint4*)(kr + 128);
            const __bf16* tr = tkv + md * 256 + ch0;
            t0n = *(const bf16x8*)tr;
            t1n = *(const bf16x8*)(tr + 8);
            u0n = *(const bf16x8*)(tr + 128);
            u1n = *(const bf16x8*)(tr + 136);
        }
        uint32_t w3 = w2;
        if (p + 16 < p1) w3 = ei[p + 16];
        float kf[16], vf[16];
        cvt4_fp8(kw.x, kf + 0); cvt4_fp8(kw.y, kf + 4);
        cvt4_fp8(kw.z, kf + 8); cvt4_fp8(kw.w, kf + 12);
        cvt4_fp8(vw.x, vf + 0); cvt4_fp8(vw.y, vf + 4);
        cvt4_fp8(vw.z, vf + 8); cvt4_fp8(vw.w, vf + 12);
        float s = 0.f;
#pragma unroll
        for (int t = 0; t < 8; t++) {
            s = fmaf(qf[t], kf[t] + (float)t0[t], s);
            s = fmaf(qf[8 + t], kf[8 + t] + (float)t1[t], s);
        }
        float pe = __expf(s * 0.25f);  // 1/sqrt(DK)
        l += pe;
#pragma unroll
        for (int t = 0; t < 8; t++) {
            a[t] = fmaf(pe, vf[t] + (float)u0[t], a[t]);
            a[8 + t] = fmaf(pe, vf[8 + t] + (float)u1[t], a[8 + t]);
        }
        kw = kwn; vw = vwn; t0 = t0n; t1 = t1n; u0 = u0n; u1 = u1n;
        w2 = w3;
        p += 8;
    }
    // ---- LDS slot-merge epilogue (same-wave produce/consume: no barrier) ----
    float* rw = red[wv] + slot * 172 + 20 * h;  // pad(16h) = 20h
    *(float4*)(rw + 0) = make_float4(a[0], a[1], a[2], a[3]);
    *(float4*)(rw + 4) = make_float4(a[4], a[5], a[6], a[7]);
    *(float4*)(rw + 8) = make_float4(a[8], a[9], a[10], a[11]);
    *(float4*)(rw + 12) = make_float4(a[12], a[13], a[14], a[15]);
    red[wv][slot * 172 + 156 + h] = l;
    asm volatile("" ::: "memory");  // keep ds_reads after ds_writes (DS in-order per wave)
    int pc = 2 * lane + 4 * (lane >> 3);  // pad(2*lane)
    int hh = lane >> 3;
    float s0 = 0.f, s1 = 0.f, ls = 0.f;
#pragma unroll
    for (int s = 0; s < 8; s++) {
        float2 v = *(const float2*)(red[wv] + s * 172 + pc);
        s0 += v.x;
        s1 += v.y;
        ls += red[wv][s * 172 + 156 + hh];
    }
    float inv = 1.0f / (ls + 1e-16f);
    bf16x2 o2;
    o2[0] = (__bf16)gelu_f(s0 * inv);
    o2[1] = (__bf16)gelu_f(s1 * inv);
    *(bf16x2*)(outb + (size_t)i * 128 + 2 * lane) = o2;
}

extern "C" void kernel_launch(void* const* d_in, const int* in_sizes, int n_in,
                              void* d_out, int out_size, void* d_ws, size_t ws_size,
                              hipStream_t stream) {
    const int N = N_NODES, E = N_EDGES;
    const int* node_attr = (const int*)d_in[0];
    const int* batch_idx = (const int*)d_in[1];
    const int* edge_index = (const int*)d_in[2];
    const int* strat_dist = (const int*)d_in[3];
    const int* strat_path = (const int*)d_in[4];
    const float* atom_emb = (const float*)d_in[5];
    const float* dist_emb = (const float*)d_in[6];
    const float* path_emb = (const float*)d_in[7];
    const float* Wq = (const float*)d_in[8];
    const float* bq = (const float*)d_in[9];
    const float* Wk = (const float*)d_in[10];
    const float* bk = (const float*)d_in[11];
    const float* Wv = (const float*)d_in[12];
    const float* bv = (const float*)d_in[13];
    const float* Wa = (const float*)d_in[14];
    const float* ba = (const float*)d_in[15];
    const float* ln1g = (const float*)d_in[16];
    const float* ln1b = (const float*)d_in[17];
    const float* Wmid = (const float*)d_in[18];
    const float* bmid = (const float*)d_in[19];
    const float* Wo = (const float*)d_in[20];
    const float* bo = (const float*)d_in[21];
    const float* ln2g = (const float*)d_in[22];
    const float* ln2b = (const float*)d_in[23];
    const float* Wout = (const float*)d_in[24];
    const float* bout = (const float*)d_in[25];
    float* out = (float*)d_out;

    const int* src = edge_index;
    const int* tgt = edge_index + E;

    // ---- workspace layout ----
    size_t NF = (size_t)N * HID;          // 6.4e6
    float* invc = (float*)d_ws;           // 256
    float* bqkv = invc + 256;             // 768
    __bf16* xb = (__bf16*)(bqkv + 768);   // NF
    __bf16* Qb = xb + NF;                 // NF
    __bf16* ab = Qb + NF;                 // NF: gelu(aggr), then h bf16 (in-place)
    __bf16* midb = ab + NF;               // 2*NF (N x 256)
    __bf16* tkv = midb + 2 * NF;          // 2 * 512*256
    __bf16* wqkvf = tkv + 262144;         // 2*49152
    __bf16* waf = wqkvf + 98304;          // 2*16384
    __bf16* wmidf = waf + 32768;          // 2*32768
    __bf16* wof = wmidf + 65536;          // 2*32768
    uint8_t* kv8 = (uint8_t*)(wof + 65536);     // N*256 bytes fp8 (K|V)
    uint32_t* ei = (uint32_t*)(kv8 + (size_t)N * 256);  // N*CAP packed
    int* cnt = (int*)(ei + (size_t)N * CAP);    // N

    // ---- prep (no scatter) + cnt zeroing ----
    hipMemsetAsync(cnt, 0, N * sizeof(int), stream);
    prep_kernel<<<26156, 256, 0, stream>>>(
        node_attr, atom_emb, xb,
        dist_emb, path_emb, Wk, Wv, tkv,
        Wq, Wa, Wmid, Wo, wqkvf, waf, wmidf, wof,
        batch_idx, bout, bq, bk, bv, invc, out, bqkv);

    const int GB = (N + 63) / 64;   // 782 row-blocks
    const int AB = (N + 3) / 4;     // 12500 attn blocks (1 node/wave)

    for (int l = 0; l < NLAYER; ++l) {
        // fused QKV (+ CSR scatter hidden behind it in layer 0)
        int scatN = (l == 0) ? SCATB : 0;
        qkv_gemm<<<scatN + 3 * GB, 256, 0, stream>>>(
            xb, wqkvf + l * 49152, bqkv + l * 384, Qb, kv8, N, scatN,
            tgt, src, strat_dist, strat_path, cnt, ei);

        // segment-softmax attention; writes gelu(aggr) bf16 into ab
        attn_kernel<<<AB, 256, 0, stream>>>(Qb, kv8, tkv + l * 131072, cnt, ei, ab);

        // h = LN1(gelu(aggr)@Wa + ba + xb) -> ab bf16 (in-place, wave-local rows)
        mfma_gemm<128, false, true, false><<<dim3(1, GB), 256, 0, stream>>>(
            ab, waf + l * 16384, ba + l * 128, xb, ln1g + l * 128, ln1b + l * 128,
            ab, nullptr, nullptr, nullptr, nullptr, N, 128);
        // mid = gelu(h@Wmid + bmid) -> bf16 N x 256
        mfma_gemm<128, true, false, false><<<dim3(2, GB), 256, 0, stream>>>(
            ab, wmidf + l * 32768, bmid + l * 256, nullptr, nullptr, nullptr,
            midb, nullptr, nullptr, nullptr, nullptr, N, 256);
        // x = LN2(mid@Wo + bo + h); last layer: fused pooled readout
        if (l < NLAYER - 1) {
            mfma_gemm<256, false, true, false><<<dim3(1, GB), 256, 0, stream>>>(
                midb, wof + l * 32768, bo + l * 128, ab, ln2g + l * 128, ln2b + l * 128,
                xb, nullptr, nullptr, nullptr, nullptr, N, 128);
        } else {
            mfma_gemm<256, false, true, true><<<dim3(1, GB), 256, 0, stream>>>(
                midb, wof + l * 32768, bo + l * 128, ab, ln2g + l * 128, ln2b + l * 128,
                nullptr, batch_idx, invc, Wout, out, N, 128);
        }
    }
}